// Round 12
// baseline (664.456 us; speedup 1.0000x reference)
//
#include <hip/hip_runtime.h>
#include <stdint.h>

#define BB 32
#define CC_ 256
#define HH 56
#define WW 56
#define TW 28          // W-tile width (2 tiles per row)
#define TCOLS 30       // TW + 2 halo columns
#define EPSV 1e-5f

typedef unsigned long long u64;

// ---------------- Weight prep: alpha, packed signs, BN folding ----------------
__global__ __launch_bounds__(256) void prep_weights(
    const float* __restrict__ w1, const float* __restrict__ w2,
    const float* __restrict__ bn1_g, const float* __restrict__ bn1_b,
    const float* __restrict__ bn1_m, const float* __restrict__ bn1_v,
    const float* __restrict__ bn2_g, const float* __restrict__ bn2_b,
    const float* __restrict__ bn2_m, const float* __restrict__ bn2_v,
    u64* __restrict__ pw1, u64* __restrict__ pw2,
    float* __restrict__ scale1, float* __restrict__ shift1,
    float* __restrict__ scale2, float* __restrict__ shift2)
{
    int co = blockIdx.x;
    int ci = threadIdx.x;
    int wv = ci >> 6, lane = ci & 63;

    float wvals[9];
    const float* wp = w1 + ((size_t)co*256 + ci)*9;
    float s1 = 0.f;
#pragma unroll
    for (int t = 0; t < 9; ++t) { wvals[t] = wp[t]; s1 += fabsf(wvals[t]); }
    float v2 = w2[(size_t)co*256 + ci];
    float s2 = fabsf(v2);

    // ballot-pack signs: bit l of word wv  <->  channel 64*wv + l  (+1 iff > 0)
#pragma unroll
    for (int t = 0; t < 9; ++t) {
        u64 b = __ballot(wvals[t] > 0.0f);
        if (lane == 0) pw1[((size_t)co*9 + t)*4 + wv] = b;
    }
    {
        u64 b = __ballot(v2 > 0.0f);
        if (lane == 0) pw2[(size_t)co*4 + wv] = b;
    }

    for (int off = 32; off > 0; off >>= 1) {
        s1 += __shfl_down(s1, off);
        s2 += __shfl_down(s2, off);
    }
    __shared__ float r1[4], r2[4];
    if (lane == 0) { r1[wv] = s1; r2[wv] = s2; }
    __syncthreads();
    if (ci == 0) {
        float a1 = (r1[0]+r1[1]+r1[2]+r1[3]) * (1.0f/2304.0f);
        float a2 = (r2[0]+r2[1]+r2[2]+r2[3]) * (1.0f/256.0f);
        float inv1 = bn1_g[co] / sqrtf(bn1_v[co] + EPSV);
        float inv2 = bn2_g[co] / sqrtf(bn2_v[co] + EPSV);
        scale1[co] = a1 * inv1;
        shift1[co] = bn1_b[co] - bn1_m[co]*inv1;
        scale2[co] = a2 * inv2;
        shift2[co] = bn2_b[co] - bn2_m[co]*inv2;
    }
}

// ---------------- Pack input: coalesced LDS stage -> ballot transpose ----------------
__global__ __launch_bounds__(256) void pack_input(
    const float* __restrict__ x, const float* __restrict__ beta1,
    u64* __restrict__ pack1)
{
    __shared__ float xrow[CC_][WW+1];      // stride 57 -> ballot reads conflict-free
    int bid = blockIdx.x;                  // n*HH + h
    int n = bid / HH, h = bid % HH;
    int tid = threadIdx.x;

    for (int idx = tid; idx < CC_*14; idx += 256) {
        int c = idx / 14, g = idx - c*14;
        float4 v = *(const float4*)(x + (((size_t)n*CC_ + c)*HH + h)*WW + 4*g);
        xrow[c][4*g+0] = v.x; xrow[c][4*g+1] = v.y;
        xrow[c][4*g+2] = v.z; xrow[c][4*g+3] = v.w;
    }
    __syncthreads();

    int wv = tid >> 6, lane = tid & 63;
    float beta = beta1[wv*64 + lane];
    u64 mine = 0;
    for (int ww = 0; ww < WW; ++ww) {
        u64 b = __ballot(xrow[wv*64 + lane][ww] > beta);
        if (ww == lane) mine = b;
    }
    if (lane < WW) pack1[((size_t)bid*WW + lane)*4 + wv] = mine;
}

// ---------------- named-register machinery (NO address-taken arrays anywhere) ----------------
#define CAT3(a,b,c) a##b##c
#define V_(S,R,Q) CAT3(S,R,Q)

// one 3x3-tap popcount contribution: window set S row R vs weight tap T (4 u64 words)
#define TAP(S,R,T) ( __builtin_popcountll(V_(S,R,0) ^ V_(W,T,0)) \
                   + __builtin_popcountll(V_(S,R,1) ^ V_(W,T,1)) \
                   + __builtin_popcountll(V_(S,R,2) ^ V_(W,T,2)) \
                   + __builtin_popcountll(V_(S,R,3) ^ V_(W,T,3)) )

// load weight tap T (4 u64) into named scalars W T 0..3
#define LDW(T) do { \
    ulonglong2 a_ = *(const ulonglong2*)(wq + (T)*4); \
    ulonglong2 b_ = *(const ulonglong2*)(wq + (T)*4 + 2); \
    V_(W,T,0)=a_.x; V_(W,T,1)=a_.y; V_(W,T,2)=b_.x; V_(W,T,3)=b_.y; } while(0)

#define PIN(v) asm volatile("" : "+v"(v))

// load packed column J (3 rows x 4 u64) into named set S (wave-uniform addr -> LDS broadcast)
#define CLOAD(S,J) do { \
    ulonglong2 x0_ = *(const ulonglong2*)&rows[0][(J)][0]; \
    ulonglong2 x1_ = *(const ulonglong2*)&rows[0][(J)][2]; \
    ulonglong2 y0_ = *(const ulonglong2*)&rows[1][(J)][0]; \
    ulonglong2 y1_ = *(const ulonglong2*)&rows[1][(J)][2]; \
    ulonglong2 z0_ = *(const ulonglong2*)&rows[2][(J)][0]; \
    ulonglong2 z1_ = *(const ulonglong2*)&rows[2][(J)][2]; \
    V_(S,0,0)=x0_.x; V_(S,0,1)=x0_.y; V_(S,0,2)=x1_.x; V_(S,0,3)=x1_.y; \
    V_(S,1,0)=y0_.x; V_(S,1,1)=y0_.y; V_(S,1,2)=y1_.x; V_(S,1,3)=y1_.y; \
    V_(S,2,0)=z0_.x; V_(S,2,1)=z0_.y; V_(S,2,2)=z1_.x; V_(S,2,3)=z1_.y; } while(0)

// full 9-tap pixel: window cols L,M,R -> output pixel P (in-place outr update)
#define PIX(L,M,R_,P) do { \
    int acc_ = TAP(L,0,0)+TAP(M,0,1)+TAP(R_,0,2) \
             + TAP(L,1,3)+TAP(M,1,4)+TAP(R_,1,5) \
             + TAP(L,2,6)+TAP(M,2,7)+TAP(R_,2,8); \
    float y_ = fmaf((float)(2304 - 2*acc_), sc1, sh1) + outr[cc][(P)]; \
    float yr_ = y_ - gam; \
    outr[cc][(P)] = fmaf(slp, fminf(yr_,0.f), fmaxf(yr_,0.f)) + zet; } while(0)

// ---------------- Fused main (lane = cout, rotating named-register window) ----------------
__global__ __launch_bounds__(256, 3) void main_fused(
    const float* __restrict__ x,
    const u64* __restrict__ pack1,
    const u64* __restrict__ pw1, const u64* __restrict__ pw2,
    const float* __restrict__ scale1, const float* __restrict__ shift1,
    const float* __restrict__ scale2, const float* __restrict__ shift2,
    const float* __restrict__ beta2,
    const float* __restrict__ pr_gamma, const float* __restrict__ pr_slope,
    const float* __restrict__ pr_zeta,
    float* __restrict__ out)
{
    __shared__ u64 rows[3][TCOLS][4];        // 2880 B
    __shared__ float outr[CC_][TW+1];        // 29696 B: x -> out_r -> final (in-place)
    __shared__ u64 p2[TW][4];                // 896 B   (total 33472 B)

    int bid = blockIdx.x;
    int tile = bid & 1;
    int nh = bid >> 1;
    int n = nh / HH, h = nh % HH;
    int w0 = tile * TW;
    int tid = threadIdx.x;
    int wv = tid >> 6;
    int lane = tid & 63;
    int cc = tid;                            // this thread's output channel

    float sc1 = scale1[cc], sh1 = shift1[cc];
    float sc2 = scale2[cc], sh2 = shift2[cc];
    float gam = pr_gamma[cc], slp = pr_slope[cc], zet = pr_zeta[cc];
    float bet2 = beta2[cc];
    const u64* wq = pw1 + (size_t)cc*36;

    // ---- 36 named weight registers, loaded once, pinned live ----
    u64 W00,W01,W02,W03, W10,W11,W12,W13, W20,W21,W22,W23;
    u64 W30,W31,W32,W33, W40,W41,W42,W43, W50,W51,W52,W53;
    u64 W60,W61,W62,W63, W70,W71,W72,W73, W80,W81,W82,W83;
    LDW(0); LDW(1); LDW(2); LDW(3); LDW(4); LDW(5); LDW(6); LDW(7); LDW(8);
    PIN(W00);PIN(W01);PIN(W02);PIN(W03); PIN(W10);PIN(W11);PIN(W12);PIN(W13);
    PIN(W20);PIN(W21);PIN(W22);PIN(W23); PIN(W30);PIN(W31);PIN(W32);PIN(W33);
    PIN(W40);PIN(W41);PIN(W42);PIN(W43); PIN(W50);PIN(W51);PIN(W52);PIN(W53);
    PIN(W60);PIN(W61);PIN(W62);PIN(W63); PIN(W70);PIN(W71);PIN(W72);PIN(W73);
    PIN(W80);PIN(W81);PIN(W82);PIN(W83);

    // ---- stage packed rows h-1,h,h+1 with w-halo (clamped; edges fixed later) ----
    {
        int hm = (h > 0) ? h-1 : 0;
        int hp = (h < HH-1) ? h+1 : HH-1;
        for (int idx = tid; idx < 3*TCOLS*4; idx += 256) {
            int r = idx / (TCOLS*4);
            int rem = idx - r*(TCOLS*4);
            int j = rem >> 2, q = rem & 3;
            int gw = w0 - 1 + j;
            gw = (gw < 0) ? 0 : ((gw > WW-1) ? WW-1 : gw);
            int hr = (r == 0) ? hm : ((r == 1) ? h : hp);
            rows[r][j][q] = pack1[((size_t)(n*HH + hr)*WW + gw)*4 + q];
        }
    }
    // ---- stage residual x tile (coalesced float4) ----
    for (int idx = tid; idx < CC_*7; idx += 256) {
        int c = idx / 7, g = idx - c*7;
        float4 v = *(const float4*)(x + (((size_t)n*CC_ + c)*HH + h)*WW + w0 + 4*g);
        outr[c][4*g+0] = v.x; outr[c][4*g+1] = v.y;
        outr[c][4*g+2] = v.z; outr[c][4*g+3] = v.w;
    }
    __syncthreads();

    bool rowU = (h > 0), rowD = (h < HH-1);

    // ---- phase 1: 3x3 binary conv + BN + residual + RPReLU ----
    u64 A00,A01,A02,A03, A10,A11,A12,A13, A20,A21,A22,A23;
    u64 B00,B01,B02,B03, B10,B11,B12,B13, B20,B21,B22,B23;
    u64 C00,C01,C02,C03, C10,C11,C12,C13, C20,C21,C22,C23;

    if (rowU && rowD) {
        // stash the edge pixel's residual (in-loop value is garbage until fix-up)
        float xe = (tile == 0) ? outr[cc][0] : outr[cc][TW-1];

        CLOAD(A,0); CLOAD(B,1);
        int p = 0;
        for (int it = 0; it < 9; ++it) {          // 27 pixels, rotation period 3
            CLOAD(C,p+2); PIX(A,B,C,p);
            CLOAD(A,p+3); PIX(B,C,A,p+1);
            CLOAD(B,p+4); PIX(C,A,B,p+2);
            p += 3;
        }
        CLOAD(C,29); PIX(A,B,C,27);               // tail pixel 27

        // fix-up the single global-edge pixel (6 valid taps), exact recompute
        if (tile == 0) {
            CLOAD(A,1); CLOAD(B,2);
            int acc = TAP(A,0,1)+TAP(B,0,2)
                    + TAP(A,1,4)+TAP(B,1,5)
                    + TAP(A,2,7)+TAP(B,2,8);
            float y = fmaf((float)(1536 - 2*acc), sc1, sh1) + xe;
            float yr = y - gam;
            outr[cc][0] = fmaf(slp, fminf(yr,0.f), fmaxf(yr,0.f)) + zet;
        } else {
            CLOAD(A,27); CLOAD(B,28);
            int acc = TAP(A,0,0)+TAP(B,0,1)
                    + TAP(A,1,3)+TAP(B,1,4)
                    + TAP(A,2,6)+TAP(B,2,7);
            float y = fmaf((float)(1536 - 2*acc), sc1, sh1) + xe;
            float yr = y - gam;
            outr[cc][TW-1] = fmaf(slp, fminf(yr,0.f), fmaxf(yr,0.f)) + zet;
        }
    } else {
        // border-h blocks (h=0 or 55): masked taps, single pass, named registers
        for (int p = 0; p < TW; ++p) {
            int w = w0 + p;
            bool colL = (w > 0), colR = (w < WW-1);
            CLOAD(A,p); CLOAD(B,p+1); CLOAD(C,p+2);
            int acc = 0, nval = 0;
            if (rowU) {
                if (colL) { acc += TAP(A,0,0); ++nval; }
                acc += TAP(B,0,1); ++nval;
                if (colR) { acc += TAP(C,0,2); ++nval; }
            }
            if (colL) { acc += TAP(A,1,3); ++nval; }
            acc += TAP(B,1,4); ++nval;
            if (colR) { acc += TAP(C,1,5); ++nval; }
            if (rowD) {
                if (colL) { acc += TAP(A,2,6); ++nval; }
                acc += TAP(B,2,7); ++nval;
                if (colR) { acc += TAP(C,2,8); ++nval; }
            }
            float y = fmaf((float)(256*nval - 2*acc), sc1, sh1) + outr[cc][p];
            float yr = y - gam;
            outr[cc][p] = fmaf(slp, fminf(yr,0.f), fmaxf(yr,0.f)) + zet;
        }
    }
    // no barrier: phase 2 reads only this thread's own outr row

    // ---- phase 2: rsign(out_r, beta2) -> packed bits per pixel ----
    {
        u64 mine = 0;
        for (int ww = 0; ww < TW; ++ww) {
            u64 b = __ballot(outr[cc][ww] > bet2);
            if (ww == lane) mine = b;
        }
        if (lane < TW) p2[lane][wv] = mine;
    }
    __syncthreads();                         // p2 consumed cross-wave

    // ---- phase 3: 1x1 binary conv + BN + residual + RPReLU (in-place outr) ----
    {
        ulonglong2 qa = *(const ulonglong2*)(pw2 + (size_t)cc*4);
        ulonglong2 qb = *(const ulonglong2*)(pw2 + (size_t)cc*4 + 2);
        u64 q0 = qa.x, q1 = qa.y, q2 = qb.x, q3 = qb.y;
        for (int p = 0; p < TW; ++p) {
            ulonglong2 a = *(const ulonglong2*)&p2[p][0];
            ulonglong2 b = *(const ulonglong2*)&p2[p][2];
            int pc = __builtin_popcountll(a.x ^ q0) + __builtin_popcountll(a.y ^ q1)
                   + __builtin_popcountll(b.x ^ q2) + __builtin_popcountll(b.y ^ q3);
            float s = (float)(256 - 2*pc);
            float y = fmaf(s, sc2, sh2) + outr[cc][p];
            float yr = y - gam;
            outr[cc][p] = fmaf(slp, fminf(yr,0.f), fmaxf(yr,0.f)) + zet;
        }
    }
    __syncthreads();                         // phase 4 reads other waves' rows

    // ---- phase 4: coalesced float4 write-out ----
    for (int idx = tid; idx < CC_*7; idx += 256) {
        int c = idx / 7, g = idx - c*7;
        float4 v;
        v.x = outr[c][4*g+0]; v.y = outr[c][4*g+1];
        v.z = outr[c][4*g+2]; v.w = outr[c][4*g+3];
        *(float4*)(out + (((size_t)n*CC_ + c)*HH + h)*WW + w0 + 4*g) = v;
    }
}

// ---------------- launcher ----------------
extern "C" void kernel_launch(void* const* d_in, const int* in_sizes, int n_in,
                              void* d_out, int out_size, void* d_ws, size_t ws_size,
                              hipStream_t stream) {
    const float* x           = (const float*)d_in[0];
    const float* rsign1_beta = (const float*)d_in[1];
    const float* w1          = (const float*)d_in[2];
    const float* bn1_g       = (const float*)d_in[3];
    const float* bn1_b       = (const float*)d_in[4];
    const float* bn1_m       = (const float*)d_in[5];
    const float* bn1_v       = (const float*)d_in[6];
    const float* rsign2_beta = (const float*)d_in[7];
    const float* w2          = (const float*)d_in[8];
    const float* bn2_g       = (const float*)d_in[9];
    const float* bn2_b       = (const float*)d_in[10];
    const float* bn2_m       = (const float*)d_in[11];
    const float* bn2_v       = (const float*)d_in[12];
    const float* pr_gamma    = (const float*)d_in[13];
    const float* pr_slope    = (const float*)d_in[14];
    const float* pr_zeta     = (const float*)d_in[15];

    char* ws = (char*)d_ws;
    u64*   pw1    = (u64*)(ws);            // 256*9*4*8   = 73728 B
    u64*   pw2    = (u64*)(ws + 73728);    // 256*4*8     =  8192 B
    float* scale1 = (float*)(ws + 81920);  // 1024 B each
    float* shift1 = (float*)(ws + 82944);
    float* scale2 = (float*)(ws + 83968);
    float* shift2 = (float*)(ws + 84992);
    u64*   pack1  = (u64*)(ws + 86016);    // 32*56*56*4*8 = 3211264 B

    prep_weights<<<256, 256, 0, stream>>>(w1, w2, bn1_g, bn1_b, bn1_m, bn1_v,
                                          bn2_g, bn2_b, bn2_m, bn2_v,
                                          pw1, pw2, scale1, shift1, scale2, shift2);
    pack_input<<<BB*HH, 256, 0, stream>>>(x, rsign1_beta, pack1);
    main_fused<<<BB*HH*2, 256, 0, stream>>>(x, pack1, pw1, pw2,
                                            scale1, shift1, scale2, shift2,
                                            rsign2_beta, pr_gamma, pr_slope, pr_zeta,
                                            (float*)d_out);
}